// Round 1
// baseline (1000.448 us; speedup 1.0000x reference)
//
#include <hip/hip_runtime.h>
#include <hip/hip_bf16.h>

#define NN 50000
#define NE 800000
#define INC 128
#define HID 64
#define OUTC 32
#define NREL 8
#define NG 64
#define SLOPE 0.2f

// ---------------- encoder: h = x @ enc_W + enc_b ----------------
__global__ __launch_bounds__(256) void enc_kernel(const float* __restrict__ x,
    const float* __restrict__ W, const float* __restrict__ b, float* __restrict__ h)
{
    __shared__ float Ws[INC*HID];           // 32 KB
    int tid = threadIdx.x;
    for (int i = tid; i < INC*HID; i += 256) Ws[i] = W[i];
    __syncthreads();
    int col = tid & 63, ty = tid >> 6;
    int base = blockIdx.x * 16;             // 16 rows/block
    float bias = b[col];
    for (int p = 0; p < 4; ++p) {
        int row = base + p*4 + ty;
        const float* xr = x + (size_t)row*INC;
        float acc = 0.f;
        #pragma unroll 8
        for (int k = 0; k < INC; ++k) acc += xr[k]*Ws[k*HID+col];
        h[(size_t)row*HID+col] = acc + bias;
    }
}

// ---------------- wq[r] = w[r]@q, wk[r] = w[r]@k  (16 x 64) ----------------
__global__ void wqk_kernel(const float* __restrict__ w, const float* __restrict__ q,
                           const float* __restrict__ k, float* __restrict__ wqk)
{
    int j = blockIdx.x;          // 0..15  (j<8: q-side rel j ; j>=8: k-side rel j-8)
    int i = threadIdx.x;         // 0..63
    int r = j & 7;
    const float* v = (j < 8) ? q : k;
    const float* wr = w + ((size_t)r*HID + i)*HID;
    float acc = 0.f;
    for (int o = 0; o < HID; ++o) acc += wr[o]*v[o];
    wqk[j*HID + i] = acc;
}

// ---------------- s[j][n] = h[n,:] . wqk[j,:]   ([16, NN]) ----------------
__global__ __launch_bounds__(256) void s_kernel(const float* __restrict__ h,
    const float* __restrict__ wqk, float* __restrict__ sbuf)
{
    __shared__ float Ws[16*65];             // padded stride 65 to dodge bank conflicts
    int tid = threadIdx.x;
    for (int i = tid; i < 16*HID; i += 256) Ws[(i>>6)*65 + (i&63)] = wqk[i];
    __syncthreads();
    int j  = tid & 15;
    int nl = tid >> 4;                       // 0..15
    int n = blockIdx.x*16 + nl;
    const float* hr = h + (size_t)n*HID;
    float acc = 0.f;
    #pragma unroll 8
    for (int kk = 0; kk < HID; ++kk) acc += hr[kk]*Ws[j*65+kk];
    sbuf[(size_t)j*NN + n] = acc;
}

// ---------------- h_all[r,n,o] = sum_i h[n,i] w[r,i,o] ----------------
#define HALL_ROWS 40
__global__ __launch_bounds__(256) void hall_kernel(const float* __restrict__ h,
    const float* __restrict__ w, float* __restrict__ h_all)
{
    __shared__ float Ws[HID*HID];           // 16 KB, w[r]
    int r = blockIdx.y;
    int tid = threadIdx.x;
    const float* wr = w + (size_t)r*HID*HID;
    for (int i = tid; i < HID*HID; i += 256) Ws[i] = wr[i];
    __syncthreads();
    int o = tid & 63, ty = tid >> 6;
    int base = blockIdx.x * HALL_ROWS;
    float* dst = h_all + ((size_t)r*NN)*HID;
    for (int p = 0; p < HALL_ROWS/4; ++p) {
        int row = base + p*4 + ty;
        const float* hr = h + (size_t)row*HID;
        float acc = 0.f;
        #pragma unroll 8
        for (int i = 0; i < HID; ++i) acc += hr[i]*Ws[i*HID+o];
        dst[(size_t)row*HID + o] = acc;
    }
}

// ---------------- init: h = bias (before scatter), ssum = 0, pooled = 0 ----------------
__global__ void init_layer_kernel(float* __restrict__ h, const float* __restrict__ b,
                                  float* __restrict__ ssum, float* __restrict__ pooled,
                                  int zero_pooled)
{
    int i = blockIdx.x*256 + threadIdx.x;
    if (i < NN*HID) h[i] = b[i & 63];
    if (i < NN) ssum[i] = 0.f;
    if (zero_pooled && i < NG*HID) pooled[i] = 0.f;
}

// ---------------- per-edge score + exp + segment-sum ----------------
__global__ void edge_alpha_kernel(const int* __restrict__ src, const int* __restrict__ dst,
                                  const int* __restrict__ et, const float* __restrict__ sbuf,
                                  float* __restrict__ ebuf, float* __restrict__ ssum)
{
    int e = blockIdx.x*256 + threadIdx.x;
    if (e >= NE) return;
    int r = et[e], s = src[e], d = dst[e];
    float alpha = sbuf[(size_t)r*NN + d] + sbuf[(size_t)(8+r)*NN + s];
    alpha = (alpha > 0.f) ? alpha : SLOPE*alpha;
    float ex = expf(alpha);                 // softmax shift-invariant; |alpha| ~ O(0.1)
    ebuf[e] = ex;
    atomicAdd(&ssum[d], ex);
}

// ---------------- normalize: ebuf[e] = a_e ----------------
__global__ void norm_kernel(float* __restrict__ ebuf, const float* __restrict__ ssum,
                            const int* __restrict__ dst)
{
    int e = blockIdx.x*256 + threadIdx.x;
    if (e < NE) ebuf[e] = ebuf[e] / fmaxf(ssum[dst[e]], 1e-16f);
}

// ---------------- aggregate: h[d,:] += a_e * h_all[r, s, :] ----------------
__global__ void edge_aggr_kernel(const int* __restrict__ src, const int* __restrict__ dst,
                                 const int* __restrict__ et, const float* __restrict__ ebuf,
                                 const float* __restrict__ h_all, float* __restrict__ hout)
{
    size_t gid = (size_t)blockIdx.x*256 + threadIdx.x;
    int e = (int)(gid >> 6);
    int c = (int)(gid & 63);
    if (e >= NE) return;
    int d = dst[e], r = et[e], s = src[e];
    float a = ebuf[e];
    float val = a * h_all[((size_t)r*NN + (size_t)s)*HID + c];
    atomicAdd(&hout[(size_t)d*HID + c], val);
}

// ---------------- relu in place ----------------
__global__ void relu_kernel(float* __restrict__ h)
{
    int i = blockIdx.x*256 + threadIdx.x;
    if (i < NN*HID) h[i] = fmaxf(h[i], 0.f);
}

// ---------------- pooling (batch is sorted -> run-length accumulate) ----------------
__global__ void pool_kernel(const float* __restrict__ h, const int* __restrict__ batch,
                            float* __restrict__ pooled)
{
    int t = blockIdx.x*256 + threadIdx.x;
    int c = t & 63;
    int chunk = t >> 6;
    if (chunk >= NN/16) return;
    int n0 = chunk*16;
    float acc = 0.f;
    int cur = batch[n0];
    for (int n = n0; n < n0+16; ++n) {
        int b = batch[n];
        if (b != cur) { atomicAdd(&pooled[cur*HID+c], acc); acc = 0.f; cur = b; }
        acc += h[(size_t)n*HID + c];
    }
    atomicAdd(&pooled[cur*HID+c], acc);
}

// ---------------- head: out = relu(pooled@linW+linb)@clfW+clfb ----------------
__global__ __launch_bounds__(256) void head_kernel(const float* __restrict__ pooled,
    const float* __restrict__ linW, const float* __restrict__ linb,
    const float* __restrict__ clfW, const float* __restrict__ clfb,
    float* __restrict__ out)
{
    __shared__ float z[NG*HID];
    __shared__ float p[NG*HID];
    int tid = threadIdx.x;
    for (int i = tid; i < NG*HID; i += 256) p[i] = pooled[i];
    __syncthreads();
    for (int idx = tid; idx < NG*HID; idx += 256) {
        int g = idx >> 6, c = idx & 63;
        float acc = linb[c];
        for (int k = 0; k < HID; ++k) acc += p[g*HID+k]*linW[k*HID+c];
        z[idx] = fmaxf(acc, 0.f);
    }
    __syncthreads();
    for (int idx = tid; idx < NG*OUTC; idx += 256) {
        int g = idx >> 5, c = idx & 31;
        float acc = clfb[c];
        for (int k = 0; k < HID; ++k) acc += z[g*HID+k]*clfW[k*OUTC+c];
        out[idx] = acc;
    }
}

// ---------------- host side ----------------
static void run_layer(const float* w, const float* q, const float* k, const float* b,
                      float* h, float* h_all, float* sbuf, float* wqk, float* ebuf,
                      float* ssum, float* pooled, int zero_pooled,
                      const int* src, const int* dst, const int* et, hipStream_t stream)
{
    wqk_kernel<<<16, 64, 0, stream>>>(w, q, k, wqk);
    s_kernel<<<NN/16, 256, 0, stream>>>(h, wqk, sbuf);
    hall_kernel<<<dim3(NN/HALL_ROWS, NREL), 256, 0, stream>>>(h, w, h_all);
    init_layer_kernel<<<(NN*HID+255)/256, 256, 0, stream>>>(h, b, ssum, pooled, zero_pooled);
    edge_alpha_kernel<<<NE/256, 256, 0, stream>>>(src, dst, et, sbuf, ebuf, ssum);
    norm_kernel<<<NE/256, 256, 0, stream>>>(ebuf, ssum, dst);
    edge_aggr_kernel<<<(int)(((size_t)NE*HID)/256), 256, 0, stream>>>(src, dst, et, ebuf, h_all, h);
}

extern "C" void kernel_launch(void* const* d_in, const int* in_sizes, int n_in,
                              void* d_out, int out_size, void* d_ws, size_t ws_size,
                              hipStream_t stream)
{
    const float* x      = (const float*)d_in[0];
    const int*   eidx   = (const int*)d_in[1];
    const int*   etype  = (const int*)d_in[2];
    const int*   batch  = (const int*)d_in[3];
    const float* enc_W  = (const float*)d_in[4];
    const float* enc_b  = (const float*)d_in[5];
    const float* w0     = (const float*)d_in[6];
    const float* q0     = (const float*)d_in[7];
    const float* k0     = (const float*)d_in[8];
    const float* b0     = (const float*)d_in[9];
    const float* w1     = (const float*)d_in[10];
    const float* q1     = (const float*)d_in[11];
    const float* k1     = (const float*)d_in[12];
    const float* b1     = (const float*)d_in[13];
    const float* lin_W  = (const float*)d_in[14];
    const float* lin_b  = (const float*)d_in[15];
    const float* clf_W  = (const float*)d_in[16];
    const float* clf_b  = (const float*)d_in[17];

    const int* src = eidx;            // edge_index[0]
    const int* dst = eidx + NE;       // edge_index[1]

    float* ws = (float*)d_ws;
    float* h      = ws;                       // NN*HID
    float* h_all  = h      + (size_t)NN*HID;  // NREL*NN*HID
    float* sbuf   = h_all  + (size_t)NREL*NN*HID; // 16*NN
    float* wqk    = sbuf   + (size_t)16*NN;   // 16*HID
    float* ebuf   = wqk    + 16*HID;          // NE
    float* ssum   = ebuf   + NE;              // NN
    float* pooled = ssum   + NN;              // NG*HID

    enc_kernel<<<NN/16, 256, 0, stream>>>(x, enc_W, enc_b, h);

    run_layer(w0, q0, k0, b0, h, h_all, sbuf, wqk, ebuf, ssum, pooled, 0,
              src, dst, etype, stream);
    relu_kernel<<<(NN*HID+255)/256, 256, 0, stream>>>(h);
    run_layer(w1, q1, k1, b1, h, h_all, sbuf, wqk, ebuf, ssum, pooled, 1,
              src, dst, etype, stream);

    pool_kernel<<<(NN/16*HID + 255)/256, 256, 0, stream>>>(h, batch, pooled);
    head_kernel<<<1, 256, 0, stream>>>(pooled, lin_W, lin_b, clf_W, clf_b, (float*)d_out);
}

// Round 2
// 372.183 us; speedup vs baseline: 2.6881x; 2.6881x over previous
//
#include <hip/hip_runtime.h>
#include <hip/hip_bf16.h>

#define NN 50000
#define NE 800000
#define INC 128
#define HID 64
#define OUTC 32
#define NREL 8
#define NG 64
#define SLOPE 0.2f

typedef unsigned int uint32;
typedef unsigned short ushort16;
typedef __attribute__((ext_vector_type(8))) short short8;
typedef __attribute__((ext_vector_type(4))) float float4v;
typedef __attribute__((ext_vector_type(4))) int int4v;

__device__ __forceinline__ float bf2f(ushort16 u) {
    union { uint32 i; float f; } v; v.i = ((uint32)u) << 16; return v.f;
}
__device__ __forceinline__ ushort16 f2bf(float f) {
    union { float f; uint32 i; } v; v.f = f;
    uint32 i = v.i;
    return (ushort16)((i + 0x7FFFu + ((i >> 16) & 1u)) >> 16);   // RNE
}

// =====================================================================
// Encoder GEMM: h_bf16[50000,64] = bf16(x[50000,128] @ enc_W[128,64] + b)
// MFMA 16x16x32 bf16. Per wave: 16-row tile, N=64 (4 col-tiles), K=128 (4 chunks).
// =====================================================================
__global__ __launch_bounds__(256) void enc_mfma(const float* __restrict__ x,
    const float* __restrict__ W, const float* __restrict__ bias,
    ushort16* __restrict__ hb)
{
    int tid = threadIdx.x, wv = tid >> 6, lane = tid & 63;
    int g = lane >> 4, lr = lane & 15;

    // B fragments (bf16 of enc_W), consistent slot mapping k = kc*32 + g*8 + j
    short8 bf[4][4];                       // [colTile][kChunk]
    for (int t = 0; t < 4; ++t)
        for (int kc = 0; kc < 4; ++kc) {
            short8 v;
            #pragma unroll
            for (int j = 0; j < 8; ++j) {
                int k = kc * 32 + g * 8 + j;
                v[j] = (short)f2bf(W[k * HID + t * 16 + lr]);
            }
            bf[t][kc] = v;
        }

    __shared__ float lds[4][16 * 65];
    float* myl = lds[wv];

    for (int tile = blockIdx.x * 4 + wv; tile < NN / 16; tile += gridDim.x * 4) {
        int row0 = tile * 16;
        const float4v* xp = (const float4v*)(x + (size_t)(row0 + lr) * INC);
        short8 af[4];
        #pragma unroll
        for (int kc = 0; kc < 4; ++kc) {
            float4v u0 = xp[kc * 8 + g * 2];
            float4v u1 = xp[kc * 8 + g * 2 + 1];
            short8 v;
            v[0] = (short)f2bf(u0[0]); v[1] = (short)f2bf(u0[1]);
            v[2] = (short)f2bf(u0[2]); v[3] = (short)f2bf(u0[3]);
            v[4] = (short)f2bf(u1[0]); v[5] = (short)f2bf(u1[1]);
            v[6] = (short)f2bf(u1[2]); v[7] = (short)f2bf(u1[3]);
            af[kc] = v;
        }
        float4v acc[4];
        #pragma unroll
        for (int t = 0; t < 4; ++t) { float4v z = {0.f,0.f,0.f,0.f}; acc[t] = z; }
        #pragma unroll
        for (int t = 0; t < 4; ++t)
            #pragma unroll
            for (int kc = 0; kc < 4; ++kc)
                acc[t] = __builtin_amdgcn_mfma_f32_16x16x32_bf16(af[kc], bf[t][kc], acc[t], 0, 0, 0);

        // C/D layout (m89-verified): col = lane&15, row = 4*(lane>>4)+i
        #pragma unroll
        for (int t = 0; t < 4; ++t)
            #pragma unroll
            for (int i = 0; i < 4; ++i)
                myl[(4 * g + i) * 65 + t * 16 + lr] = acc[t][i];
        __asm volatile("s_waitcnt lgkmcnt(0)" ::: "memory");

        // repack: lane -> row lane>>2, cols (lane&3)*16..+15 ; +bias, cvt bf16, coalesced store
        int row = lane >> 2, cg = lane & 3;
        const float* srcp = myl + row * 65 + cg * 16;
        uint32 p[8];
        #pragma unroll
        for (int j = 0; j < 8; ++j) {
            float v0 = srcp[2 * j]     + bias[cg * 16 + 2 * j];
            float v1 = srcp[2 * j + 1] + bias[cg * 16 + 2 * j + 1];
            p[j] = (uint32)f2bf(v0) | ((uint32)f2bf(v1) << 16);
        }
        int4v s0 = {(int)p[0], (int)p[1], (int)p[2], (int)p[3]};
        int4v s1 = {(int)p[4], (int)p[5], (int)p[6], (int)p[7]};
        int4v* op = (int4v*)(hb + (size_t)(row0 + row) * HID + cg * 16);
        op[0] = s0; op[1] = s1;
        __asm volatile("s_waitcnt lgkmcnt(0)" ::: "memory");   // myl reused next iter
    }
}

// =====================================================================
// h_all GEMM: hall[r][50000,64] = bf16(h_bf16 @ w[r])   (K=64: 2 chunks)
// =====================================================================
__global__ __launch_bounds__(256) void hall_mfma(const ushort16* __restrict__ hb,
    const float* __restrict__ w, ushort16* __restrict__ hall)
{
    int r = blockIdx.y;
    int tid = threadIdx.x, wv = tid >> 6, lane = tid & 63;
    int g = lane >> 4, lr = lane & 15;
    const float* wr = w + (size_t)r * HID * HID;

    short8 bf[4][2];
    for (int t = 0; t < 4; ++t)
        for (int kc = 0; kc < 2; ++kc) {
            short8 v;
            #pragma unroll
            for (int j = 0; j < 8; ++j) {
                int k = kc * 32 + g * 8 + j;
                v[j] = (short)f2bf(wr[k * HID + t * 16 + lr]);
            }
            bf[t][kc] = v;
        }

    __shared__ float lds[4][16 * 65];
    float* myl = lds[wv];
    ushort16* outr = hall + (size_t)r * NN * HID;

    for (int tile = blockIdx.x * 4 + wv; tile < NN / 16; tile += gridDim.x * 4) {
        int row0 = tile * 16;
        const short8* ap = (const short8*)(hb + (size_t)(row0 + lr) * HID);
        short8 a0 = ap[g];       // k = g*8..+7
        short8 a1 = ap[4 + g];   // k = 32 + g*8..+7
        float4v acc[4];
        #pragma unroll
        for (int t = 0; t < 4; ++t) { float4v z = {0.f,0.f,0.f,0.f}; acc[t] = z; }
        #pragma unroll
        for (int t = 0; t < 4; ++t) {
            acc[t] = __builtin_amdgcn_mfma_f32_16x16x32_bf16(a0, bf[t][0], acc[t], 0, 0, 0);
            acc[t] = __builtin_amdgcn_mfma_f32_16x16x32_bf16(a1, bf[t][1], acc[t], 0, 0, 0);
        }
        #pragma unroll
        for (int t = 0; t < 4; ++t)
            #pragma unroll
            for (int i = 0; i < 4; ++i)
                myl[(4 * g + i) * 65 + t * 16 + lr] = acc[t][i];
        __asm volatile("s_waitcnt lgkmcnt(0)" ::: "memory");

        int row = lane >> 2, cg = lane & 3;
        const float* srcp = myl + row * 65 + cg * 16;
        uint32 p[8];
        #pragma unroll
        for (int j = 0; j < 8; ++j)
            p[j] = (uint32)f2bf(srcp[2 * j]) | ((uint32)f2bf(srcp[2 * j + 1]) << 16);
        int4v s0 = {(int)p[0], (int)p[1], (int)p[2], (int)p[3]};
        int4v s1 = {(int)p[4], (int)p[5], (int)p[6], (int)p[7]};
        int4v* op = (int4v*)(outr + (size_t)(row0 + row) * HID + cg * 16);
        op[0] = s0; op[1] = s1;
        __asm volatile("s_waitcnt lgkmcnt(0)" ::: "memory");
    }
}

// ---------------- wq[r] = w[r]@q, wk[r] = w[r]@k  (16 x 64, f32) ----------------
__global__ void wqk_kernel(const float* __restrict__ w, const float* __restrict__ q,
                           const float* __restrict__ k, float* __restrict__ wqk)
{
    int j = blockIdx.x;          // 0..15
    int i = threadIdx.x;         // 0..63
    int r = j & 7;
    const float* v = (j < 8) ? q : k;
    const float* wr = w + ((size_t)r * HID + i) * HID;
    float acc = 0.f;
    for (int o = 0; o < HID; ++o) acc += wr[o] * v[o];
    wqk[j * HID + i] = acc;
}

// ---------------- s[j][n] = h[n,:] . wqk[j,:]   ([16, NN]) ----------------
__global__ __launch_bounds__(256) void s_kernel(const ushort16* __restrict__ hb,
    const float* __restrict__ wqk, float* __restrict__ sbuf)
{
    __shared__ float Ws[16 * 65];
    int tid = threadIdx.x;
    for (int i = tid; i < 16 * HID; i += 256) Ws[(i >> 6) * 65 + (i & 63)] = wqk[i];
    __syncthreads();
    int j = tid & 15;
    int nl = tid >> 4;
    int n = blockIdx.x * 16 + nl;
    const ushort16* hr = hb + (size_t)n * HID;
    float acc = 0.f;
    #pragma unroll 8
    for (int kk = 0; kk < HID; ++kk) acc += bf2f(hr[kk]) * Ws[j * 65 + kk];
    sbuf[(size_t)j * NN + n] = acc;
}

// ---------------- CSR build ----------------
__global__ void count_kernel(const int* __restrict__ dst, int* __restrict__ cnt)
{
    int e = blockIdx.x * 256 + threadIdx.x;
    if (e < NE) atomicAdd(&cnt[dst[e]], 1);
}

__global__ __launch_bounds__(1024) void scan_kernel(const int* __restrict__ cnt,
                                                    int* __restrict__ rowptr)
{
    __shared__ int ps[1024];
    int t = threadIdx.x;
    const int CH = (NN + 1023) / 1024;   // 49
    int s0 = t * CH, s1 = (s0 + CH < NN) ? s0 + CH : NN;
    if (s0 > NN) s0 = NN;
    int sum = 0;
    for (int i = s0; i < s1; ++i) sum += cnt[i];
    ps[t] = sum;
    __syncthreads();
    for (int off = 1; off < 1024; off <<= 1) {
        int v = (t >= off) ? ps[t - off] : 0;
        __syncthreads();
        ps[t] += v;
        __syncthreads();
    }
    int run = ps[t] - sum;               // exclusive prefix
    for (int i = s0; i < s1; ++i) { rowptr[i] = run; run += cnt[i]; }
    if (t == 0) rowptr[NN] = NE;
}

__global__ void scatter_kernel(const int* __restrict__ src, const int* __restrict__ dst,
    const int* __restrict__ et, const int* __restrict__ rowptr,
    int* __restrict__ cur, uint32* __restrict__ edges)
{
    int e = blockIdx.x * 256 + threadIdx.x;
    if (e >= NE) return;
    int d = dst[e];
    int pos = rowptr[d] + atomicAdd(&cur[d], 1);
    edges[pos] = (uint32)src[e] | ((uint32)et[e] << 16);
}

// =====================================================================
// Fused per-dst softmax + aggregate + bias (+relu). One wave per node.
// out = (sum_e exp(alpha_e) * hall[r_e, s_e, :]) / sum_e exp(alpha_e) + b
// =====================================================================
__global__ __launch_bounds__(256) void agg_kernel(const int* __restrict__ rowptr,
    const uint32* __restrict__ edges, const float* __restrict__ sbuf,
    const ushort16* __restrict__ hall, const float* __restrict__ bias,
    ushort16* __restrict__ out_bf, float* __restrict__ out_f32, int do_relu)
{
    int wv = threadIdx.x >> 6, lane = threadIdx.x & 63;
    int d = blockIdx.x * 4 + wv;
    if (d >= NN) return;
    int row0 = rowptr[d];
    int deg = rowptr[d + 1] - row0;

    float acc = 0.f, ssum = 0.f;
    for (int base = 0; base < deg; base += 64) {
        int jj = base + lane;
        float ex = 0.f; uint32 pk = 0;
        if (jj < deg) {
            pk = edges[row0 + jj];
            int s = (int)(pk & 0xFFFFu), rr = (int)(pk >> 16);
            float alpha = sbuf[rr * NN + d] + sbuf[(8 + rr) * NN + s];
            alpha = (alpha > 0.f) ? alpha : SLOPE * alpha;
            ex = __expf(alpha);
        }
        ssum += ex;
        int cnt = (deg - base < 64) ? deg - base : 64;
        for (int qq = 0; qq < cnt; ++qq) {
            float a = __shfl(ex, qq);
            uint32 pq = (uint32)__shfl((int)pk, qq);
            int s = (int)(pq & 0xFFFFu), rr = (int)((pq >> 16) & 7u);
            acc += a * bf2f(hall[((size_t)rr * NN + s) * HID + lane]);
        }
    }
    #pragma unroll
    for (int o = 32; o; o >>= 1) ssum += __shfl_xor(ssum, o);

    float outv = acc / fmaxf(ssum, 1e-16f) + bias[lane];
    if (do_relu) {
        outv = fmaxf(outv, 0.f);
        out_bf[(size_t)d * HID + lane] = f2bf(outv);
    } else {
        out_f32[(size_t)d * HID + lane] = outv;
    }
}

// ---------------- pooling (batch sorted -> run-length accumulate) ----------------
__global__ void pool_kernel(const float* __restrict__ h, const int* __restrict__ batch,
                            float* __restrict__ pooled)
{
    int t = blockIdx.x * 256 + threadIdx.x;
    int c = t & 63;
    int chunk = t >> 6;
    if (chunk >= NN / 16) return;
    int n0 = chunk * 16;
    float acc = 0.f;
    int cur = batch[n0];
    for (int n = n0; n < n0 + 16; ++n) {
        int b = batch[n];
        if (b != cur) { atomicAdd(&pooled[cur * HID + c], acc); acc = 0.f; cur = b; }
        acc += h[(size_t)n * HID + c];
    }
    atomicAdd(&pooled[cur * HID + c], acc);
}

// ---------------- head ----------------
__global__ __launch_bounds__(256) void head_kernel(const float* __restrict__ pooled,
    const float* __restrict__ linW, const float* __restrict__ linb,
    const float* __restrict__ clfW, const float* __restrict__ clfb,
    float* __restrict__ out)
{
    __shared__ float z[NG * HID];
    __shared__ float p[NG * HID];
    int tid = threadIdx.x;
    for (int i = tid; i < NG * HID; i += 256) p[i] = pooled[i];
    __syncthreads();
    for (int idx = tid; idx < NG * HID; idx += 256) {
        int g = idx >> 6, c = idx & 63;
        float acc = linb[c];
        for (int k = 0; k < HID; ++k) acc += p[g * HID + k] * linW[k * HID + c];
        z[idx] = fmaxf(acc, 0.f);
    }
    __syncthreads();
    for (int idx = tid; idx < NG * OUTC; idx += 256) {
        int g = idx >> 5, c = idx & 31;
        float acc = clfb[c];
        for (int k = 0; k < HID; ++k) acc += z[g * HID + k] * clfW[k * OUTC + c];
        out[idx] = acc;
    }
}

// ---------------- host side ----------------
extern "C" void kernel_launch(void* const* d_in, const int* in_sizes, int n_in,
                              void* d_out, int out_size, void* d_ws, size_t ws_size,
                              hipStream_t stream)
{
    const float* x      = (const float*)d_in[0];
    const int*   eidx   = (const int*)d_in[1];
    const int*   etype  = (const int*)d_in[2];
    const int*   batch  = (const int*)d_in[3];
    const float* enc_W  = (const float*)d_in[4];
    const float* enc_b  = (const float*)d_in[5];
    const float* w0     = (const float*)d_in[6];
    const float* q0     = (const float*)d_in[7];
    const float* k0     = (const float*)d_in[8];
    const float* b0     = (const float*)d_in[9];
    const float* w1     = (const float*)d_in[10];
    const float* q1     = (const float*)d_in[11];
    const float* k1     = (const float*)d_in[12];
    const float* b1     = (const float*)d_in[13];
    const float* lin_W  = (const float*)d_in[14];
    const float* lin_b  = (const float*)d_in[15];
    const float* clf_W  = (const float*)d_in[16];
    const float* clf_b  = (const float*)d_in[17];

    const int* srcp = eidx;
    const int* dstp = eidx + NE;

    // workspace carve (all 256B-aligned by construction)
    char* wsb = (char*)d_ws;
    ushort16* h_bf    = (ushort16*)wsb;                 wsb += (size_t)NN * HID * 2;      // 6.4MB
    ushort16* hall_bf = (ushort16*)wsb;                 wsb += (size_t)NREL * NN * HID * 2; // 51.2MB
    float*    h_f     = (float*)wsb;                    wsb += (size_t)NN * HID * 4;      // 12.8MB
    float*    sbuf    = (float*)wsb;                    wsb += (size_t)16 * NN * 4;       // 3.2MB
    float*    wqk     = (float*)wsb;                    wsb += 16 * HID * 4;
    float*    pooled  = (float*)wsb;                    wsb += NG * HID * 4;
    int*      cnt     = (int*)wsb;                      wsb += (size_t)NN * 4;
    int*      rowptr  = (int*)wsb;                      wsb += (size_t)(NN + 64) * 4;
    uint32*   edges_s = (uint32*)wsb;                   wsb += (size_t)NE * 4;            // 3.2MB

    // ---- CSR build (once, reused by both layers) ----
    hipMemsetAsync(cnt, 0, (size_t)NN * 4, stream);
    count_kernel<<<(NE + 255) / 256, 256, 0, stream>>>(dstp, cnt);
    scan_kernel<<<1, 1024, 0, stream>>>(cnt, rowptr);
    hipMemsetAsync(cnt, 0, (size_t)NN * 4, stream);
    scatter_kernel<<<(NE + 255) / 256, 256, 0, stream>>>(srcp, dstp, etype, rowptr, cnt, edges_s);

    // ---- encoder ----
    enc_mfma<<<256, 256, 0, stream>>>(x, enc_W, enc_b, h_bf);

    // ---- layer 0 ----
    wqk_kernel<<<16, 64, 0, stream>>>(w0, q0, k0, wqk);
    s_kernel<<<NN / 16, 256, 0, stream>>>(h_bf, wqk, sbuf);
    hall_mfma<<<dim3(256, NREL), 256, 0, stream>>>(h_bf, w0, hall_bf);
    agg_kernel<<<(NN + 3) / 4, 256, 0, stream>>>(rowptr, edges_s, sbuf, hall_bf, b0,
                                                 h_bf, (float*)nullptr, 1);

    // ---- layer 1 ----
    wqk_kernel<<<16, 64, 0, stream>>>(w1, q1, k1, wqk);
    s_kernel<<<NN / 16, 256, 0, stream>>>(h_bf, wqk, sbuf);
    hall_mfma<<<dim3(256, NREL), 256, 0, stream>>>(h_bf, w1, hall_bf);
    agg_kernel<<<(NN + 3) / 4, 256, 0, stream>>>(rowptr, edges_s, sbuf, hall_bf, b1,
                                                 (ushort16*)nullptr, h_f, 0);

    // ---- pool + head ----
    hipMemsetAsync(pooled, 0, (size_t)NG * HID * 4, stream);
    pool_kernel<<<(NN / 16 * HID + 255) / 256, 256, 0, stream>>>(h_f, batch, pooled);
    head_kernel<<<1, 256, 0, stream>>>(pooled, lin_W, lin_b, clf_W, clf_b, (float*)d_out);
}

// Round 3
// 279.644 us; speedup vs baseline: 3.5776x; 1.3309x over previous
//
#include <hip/hip_runtime.h>
#include <hip/hip_bf16.h>

#define NN 50000
#define NE 800000
#define INC 128
#define HID 64
#define OUTC 32
#define NREL 8
#define NG 64
#define SLOPE 0.2f

typedef unsigned int uint32;
typedef unsigned short ushort16;
typedef __attribute__((ext_vector_type(8))) short short8;
typedef __attribute__((ext_vector_type(4))) short short4v;
typedef __attribute__((ext_vector_type(4))) float float4v;
typedef __attribute__((ext_vector_type(4))) int int4v;
typedef __attribute__((ext_vector_type(2))) int int2v;

__device__ __forceinline__ float bf2f(ushort16 u) {
    union { uint32 i; float f; } v; v.i = ((uint32)u) << 16; return v.f;
}
__device__ __forceinline__ ushort16 f2bf(float f) {
    union { float f; uint32 i; } v; v.f = f;
    uint32 i = v.i;
    return (ushort16)((i + 0x7FFFu + ((i >> 16) & 1u)) >> 16);   // RNE
}

// =====================================================================
// Encoder GEMM: h_bf16[50000,64] = bf16(x[50000,128] @ enc_W[128,64] + b)
// =====================================================================
__global__ __launch_bounds__(256) void enc_mfma(const float* __restrict__ x,
    const float* __restrict__ W, const float* __restrict__ bias,
    ushort16* __restrict__ hb)
{
    int tid = threadIdx.x, wv = tid >> 6, lane = tid & 63;
    int g = lane >> 4, lr = lane & 15;

    short8 bf[4][4];                       // [colTile][kChunk]
    for (int t = 0; t < 4; ++t)
        for (int kc = 0; kc < 4; ++kc) {
            short8 v;
            #pragma unroll
            for (int j = 0; j < 8; ++j) {
                int k = kc * 32 + g * 8 + j;
                v[j] = (short)f2bf(W[k * HID + t * 16 + lr]);
            }
            bf[t][kc] = v;
        }

    __shared__ float lds[4][16 * 65];
    float* myl = lds[wv];

    for (int tile = blockIdx.x * 4 + wv; tile < NN / 16; tile += gridDim.x * 4) {
        int row0 = tile * 16;
        const float4v* xp = (const float4v*)(x + (size_t)(row0 + lr) * INC);
        short8 af[4];
        #pragma unroll
        for (int kc = 0; kc < 4; ++kc) {
            float4v u0 = xp[kc * 8 + g * 2];
            float4v u1 = xp[kc * 8 + g * 2 + 1];
            short8 v;
            v[0] = (short)f2bf(u0[0]); v[1] = (short)f2bf(u0[1]);
            v[2] = (short)f2bf(u0[2]); v[3] = (short)f2bf(u0[3]);
            v[4] = (short)f2bf(u1[0]); v[5] = (short)f2bf(u1[1]);
            v[6] = (short)f2bf(u1[2]); v[7] = (short)f2bf(u1[3]);
            af[kc] = v;
        }
        float4v acc[4];
        #pragma unroll
        for (int t = 0; t < 4; ++t) { float4v z = {0.f,0.f,0.f,0.f}; acc[t] = z; }
        #pragma unroll
        for (int t = 0; t < 4; ++t)
            #pragma unroll
            for (int kc = 0; kc < 4; ++kc)
                acc[t] = __builtin_amdgcn_mfma_f32_16x16x32_bf16(af[kc], bf[t][kc], acc[t], 0, 0, 0);

        #pragma unroll
        for (int t = 0; t < 4; ++t)
            #pragma unroll
            for (int i = 0; i < 4; ++i)
                myl[(4 * g + i) * 65 + t * 16 + lr] = acc[t][i];
        __asm volatile("s_waitcnt lgkmcnt(0)" ::: "memory");

        int row = lane >> 2, cg = lane & 3;
        const float* srcp = myl + row * 65 + cg * 16;
        uint32 p[8];
        #pragma unroll
        for (int j = 0; j < 8; ++j) {
            float v0 = srcp[2 * j]     + bias[cg * 16 + 2 * j];
            float v1 = srcp[2 * j + 1] + bias[cg * 16 + 2 * j + 1];
            p[j] = (uint32)f2bf(v0) | ((uint32)f2bf(v1) << 16);
        }
        int4v s0 = {(int)p[0], (int)p[1], (int)p[2], (int)p[3]};
        int4v s1 = {(int)p[4], (int)p[5], (int)p[6], (int)p[7]};
        int4v* op = (int4v*)(hb + (size_t)(row0 + row) * HID + cg * 16);
        op[0] = s0; op[1] = s1;
        __asm volatile("s_waitcnt lgkmcnt(0)" ::: "memory");
    }
}

// =====================================================================
// h_all GEMM: hall[r][50000,64] = bf16(h_bf16 @ w[r])
// =====================================================================
__global__ __launch_bounds__(256) void hall_mfma(const ushort16* __restrict__ hb,
    const float* __restrict__ w, ushort16* __restrict__ hall)
{
    int r = blockIdx.y;
    int tid = threadIdx.x, wv = tid >> 6, lane = tid & 63;
    int g = lane >> 4, lr = lane & 15;
    const float* wr = w + (size_t)r * HID * HID;

    short8 bf[4][2];
    for (int t = 0; t < 4; ++t)
        for (int kc = 0; kc < 2; ++kc) {
            short8 v;
            #pragma unroll
            for (int j = 0; j < 8; ++j) {
                int k = kc * 32 + g * 8 + j;
                v[j] = (short)f2bf(wr[k * HID + t * 16 + lr]);
            }
            bf[t][kc] = v;
        }

    __shared__ float lds[4][16 * 65];
    float* myl = lds[wv];
    ushort16* outr = hall + (size_t)r * NN * HID;

    for (int tile = blockIdx.x * 4 + wv; tile < NN / 16; tile += gridDim.x * 4) {
        int row0 = tile * 16;
        const short8* ap = (const short8*)(hb + (size_t)(row0 + lr) * HID);
        short8 a0 = ap[g];
        short8 a1 = ap[4 + g];
        float4v acc[4];
        #pragma unroll
        for (int t = 0; t < 4; ++t) { float4v z = {0.f,0.f,0.f,0.f}; acc[t] = z; }
        #pragma unroll
        for (int t = 0; t < 4; ++t) {
            acc[t] = __builtin_amdgcn_mfma_f32_16x16x32_bf16(a0, bf[t][0], acc[t], 0, 0, 0);
            acc[t] = __builtin_amdgcn_mfma_f32_16x16x32_bf16(a1, bf[t][1], acc[t], 0, 0, 0);
        }
        #pragma unroll
        for (int t = 0; t < 4; ++t)
            #pragma unroll
            for (int i = 0; i < 4; ++i)
                myl[(4 * g + i) * 65 + t * 16 + lr] = acc[t][i];
        __asm volatile("s_waitcnt lgkmcnt(0)" ::: "memory");

        int row = lane >> 2, cg = lane & 3;
        const float* srcp = myl + row * 65 + cg * 16;
        uint32 p[8];
        #pragma unroll
        for (int j = 0; j < 8; ++j)
            p[j] = (uint32)f2bf(srcp[2 * j]) | ((uint32)f2bf(srcp[2 * j + 1]) << 16);
        int4v s0 = {(int)p[0], (int)p[1], (int)p[2], (int)p[3]};
        int4v s1 = {(int)p[4], (int)p[5], (int)p[6], (int)p[7]};
        int4v* op = (int4v*)(outr + (size_t)(row0 + row) * HID + cg * 16);
        op[0] = s0; op[1] = s1;
        __asm volatile("s_waitcnt lgkmcnt(0)" ::: "memory");
    }
}

// ---------------- wq[r] = w[r]@q, wk[r] = w[r]@k  (16 x 64, f32) ----------------
__global__ void wqk_kernel(const float* __restrict__ w, const float* __restrict__ q,
                           const float* __restrict__ k, float* __restrict__ wqk)
{
    int j = blockIdx.x;
    int i = threadIdx.x;
    int r = j & 7;
    const float* v = (j < 8) ? q : k;
    const float* wr = w + ((size_t)r * HID + i) * HID;
    float acc = 0.f;
    for (int o = 0; o < HID; ++o) acc += wr[o] * v[o];
    wqk[j * HID + i] = acc;
}

// ---------------- s[j][n] = h[n,:] . wqk[j,:]   ([16, NN]) ----------------
__global__ __launch_bounds__(256) void s_kernel(const ushort16* __restrict__ hb,
    const float* __restrict__ wqk, float* __restrict__ sbuf)
{
    __shared__ float Ws[16 * 65];
    __shared__ short4v Hs[16][17];          // 16 rows x 64 bf16 (padded)
    int tid = threadIdx.x;
    for (int i = tid; i < 16 * HID; i += 256) Ws[(i >> 6) * 65 + (i & 63)] = wqk[i];
    int n0 = blockIdx.x * 16;
    {
        int row = tid >> 4, ch = tid & 15;
        Hs[row][ch] = *(const short4v*)(hb + (size_t)(n0 + row) * HID + ch * 4);
    }
    __syncthreads();
    int j = tid & 15, nl = tid >> 4;
    short4v hreg[16];
    #pragma unroll
    for (int c = 0; c < 16; ++c) hreg[c] = Hs[nl][c];
    float acc = 0.f;
    #pragma unroll
    for (int c = 0; c < 16; ++c)
        #pragma unroll
        for (int u = 0; u < 4; ++u)
            acc += bf2f((ushort16)hreg[c][u]) * Ws[j * 65 + c * 4 + u];
    sbuf[(size_t)j * NN + n0 + nl] = acc;
}

// ---------------- CSR build ----------------
__global__ void count_kernel(const int* __restrict__ dst, int* __restrict__ cnt)
{
    int e = blockIdx.x * 256 + threadIdx.x;
    if (e < NE) atomicAdd(&cnt[dst[e]], 1);
}

// exclusive scan of cnt[NN] -> rowptr, 3 phases
__global__ __launch_bounds__(256) void scanA(const int* __restrict__ cnt,
    int* __restrict__ rowptr, int* __restrict__ bsum)
{
    int tid = threadIdx.x;
    int i = blockIdx.x * 256 + tid;
    int v = (i < NN) ? cnt[i] : 0;
    int lane = tid & 63, wv = tid >> 6;
    int x = v;
    #pragma unroll
    for (int o = 1; o < 64; o <<= 1) {
        int t = __shfl_up(x, o);
        if (lane >= o) x += t;
    }
    __shared__ int wtot[4];
    if (lane == 63) wtot[wv] = x;
    __syncthreads();
    int woff = 0;
    #pragma unroll
    for (int w = 0; w < 3; ++w) if (w < wv) woff += wtot[w];
    if (i < NN) rowptr[i] = x - v + woff;
    if (tid == 255) bsum[blockIdx.x] = x + woff;
}

__global__ __launch_bounds__(256) void scanB(int* __restrict__ bsum, int nb)
{
    int tid = threadIdx.x;
    int v = (tid < nb) ? bsum[tid] : 0;
    int lane = tid & 63, wv = tid >> 6;
    int x = v;
    #pragma unroll
    for (int o = 1; o < 64; o <<= 1) {
        int t = __shfl_up(x, o);
        if (lane >= o) x += t;
    }
    __shared__ int wtot[4];
    if (lane == 63) wtot[wv] = x;
    __syncthreads();
    int woff = 0;
    #pragma unroll
    for (int w = 0; w < 3; ++w) if (w < wv) woff += wtot[w];
    if (tid < nb) bsum[tid] = x - v + woff;
}

__global__ void scanC(int* __restrict__ rowptr, const int* __restrict__ bsum)
{
    int i = blockIdx.x * 256 + threadIdx.x;
    if (i < NN) rowptr[i] += bsum[i >> 8];
    if (i == 0) rowptr[NN] = NE;
}

__global__ void scatter_kernel(const int* __restrict__ src, const int* __restrict__ dst,
    const int* __restrict__ et, const int* __restrict__ rowptr,
    int* __restrict__ cur, uint32* __restrict__ edges)
{
    int e = blockIdx.x * 256 + threadIdx.x;
    if (e >= NE) return;
    int d = dst[e];
    int pos = rowptr[d] + atomicAdd(&cur[d], 1);
    edges[pos] = (uint32)src[e] | ((uint32)et[e] << 16);
}

// =====================================================================
// Fused per-dst softmax + aggregate + bias (+relu).
// One wave per node; 4 groups of 16 lanes, each group owns one edge;
// lane covers 4 channels. Cross-group butterfly at the end.
// =====================================================================
__global__ __launch_bounds__(256) void agg_kernel(const int* __restrict__ rowptr,
    const uint32* __restrict__ edges, const float* __restrict__ sbuf,
    const ushort16* __restrict__ hall, const float* __restrict__ bias,
    ushort16* __restrict__ out_bf, float* __restrict__ out_f32, int do_relu)
{
    int wv = threadIdx.x >> 6, lane = threadIdx.x & 63;
    int d = blockIdx.x * 4 + wv;
    if (d >= NN) return;
    int row0 = rowptr[d];
    int deg = rowptr[d + 1] - row0;
    int g = lane >> 4, cl = lane & 15;

    // per-relation dst scores in lanes 0..7
    float myq = (lane < 8) ? sbuf[lane * NN + d] : 0.f;

    float4v acc = {0.f, 0.f, 0.f, 0.f};
    float ssum = 0.f;
    for (int base = 0; base < deg; base += 4) {
        int j = base + g;
        bool valid = (j < deg);
        uint32 pk = valid ? edges[row0 + j] : 0u;
        int s = (int)(pk & 0xFFFFu), rr = (int)((pk >> 16) & 7u);
        float ex = 0.f;
        if (valid) {
            float alpha = __shfl(myq, rr) + sbuf[(8 + rr) * NN + s];
            alpha = (alpha > 0.f) ? alpha : SLOPE * alpha;
            ex = __expf(alpha);
        }
        ssum += ex;
        short4v hv = *(const short4v*)(hall + ((size_t)rr * NN + s) * HID + cl * 4);
        acc[0] += ex * bf2f((ushort16)hv[0]);
        acc[1] += ex * bf2f((ushort16)hv[1]);
        acc[2] += ex * bf2f((ushort16)hv[2]);
        acc[3] += ex * bf2f((ushort16)hv[3]);
    }
    // reduce across the 4 groups (channels aligned; ssum uniform within group)
    #pragma unroll
    for (int o = 16; o < 64; o <<= 1) {
        acc[0] += __shfl_xor(acc[0], o);
        acc[1] += __shfl_xor(acc[1], o);
        acc[2] += __shfl_xor(acc[2], o);
        acc[3] += __shfl_xor(acc[3], o);
        ssum   += __shfl_xor(ssum, o);
    }

    if (lane < 16) {
        float inv = 1.f / fmaxf(ssum, 1e-16f);
        float o0 = acc[0] * inv + bias[cl * 4 + 0];
        float o1 = acc[1] * inv + bias[cl * 4 + 1];
        float o2 = acc[2] * inv + bias[cl * 4 + 2];
        float o3 = acc[3] * inv + bias[cl * 4 + 3];
        if (do_relu) {
            o0 = fmaxf(o0, 0.f); o1 = fmaxf(o1, 0.f);
            o2 = fmaxf(o2, 0.f); o3 = fmaxf(o3, 0.f);
            uint32 lo = (uint32)f2bf(o0) | ((uint32)f2bf(o1) << 16);
            uint32 hi = (uint32)f2bf(o2) | ((uint32)f2bf(o3) << 16);
            int2v pk2 = {(int)lo, (int)hi};
            *(int2v*)(out_bf + (size_t)d * HID + cl * 4) = pk2;
        } else {
            float4v ov = {o0, o1, o2, o3};
            *(float4v*)(out_f32 + (size_t)d * HID + cl * 4) = ov;
        }
    }
}

// ---------------- pooling (batch sorted -> run-length accumulate) ----------------
__global__ void pool_kernel(const float* __restrict__ h, const int* __restrict__ batch,
                            float* __restrict__ pooled)
{
    int t = blockIdx.x * 256 + threadIdx.x;
    int c = t & 63;
    int chunk = t >> 6;
    if (chunk >= NN / 16) return;
    int n0 = chunk * 16;
    float acc = 0.f;
    int cur = batch[n0];
    for (int n = n0; n < n0 + 16; ++n) {
        int b = batch[n];
        if (b != cur) { atomicAdd(&pooled[cur * HID + c], acc); acc = 0.f; cur = b; }
        acc += h[(size_t)n * HID + c];
    }
    atomicAdd(&pooled[cur * HID + c], acc);
}

// ---------------- head ----------------
__global__ __launch_bounds__(256) void head_kernel(const float* __restrict__ pooled,
    const float* __restrict__ linW, const float* __restrict__ linb,
    const float* __restrict__ clfW, const float* __restrict__ clfb,
    float* __restrict__ out)
{
    __shared__ float z[NG * HID];
    __shared__ float p[NG * HID];
    int tid = threadIdx.x;
    for (int i = tid; i < NG * HID; i += 256) p[i] = pooled[i];
    __syncthreads();
    for (int idx = tid; idx < NG * HID; idx += 256) {
        int g = idx >> 6, c = idx & 63;
        float acc = linb[c];
        for (int k = 0; k < HID; ++k) acc += p[g * HID + k] * linW[k * HID + c];
        z[idx] = fmaxf(acc, 0.f);
    }
    __syncthreads();
    for (int idx = tid; idx < NG * OUTC; idx += 256) {
        int g = idx >> 5, c = idx & 31;
        float acc = clfb[c];
        for (int k = 0; k < HID; ++k) acc += z[g * HID + k] * clfW[k * OUTC + c];
        out[idx] = acc;
    }
}

// ---------------- host side ----------------
extern "C" void kernel_launch(void* const* d_in, const int* in_sizes, int n_in,
                              void* d_out, int out_size, void* d_ws, size_t ws_size,
                              hipStream_t stream)
{
    const float* x      = (const float*)d_in[0];
    const int*   eidx   = (const int*)d_in[1];
    const int*   etype  = (const int*)d_in[2];
    const int*   batch  = (const int*)d_in[3];
    const float* enc_W  = (const float*)d_in[4];
    const float* enc_b  = (const float*)d_in[5];
    const float* w0     = (const float*)d_in[6];
    const float* q0     = (const float*)d_in[7];
    const float* k0     = (const float*)d_in[8];
    const float* b0     = (const float*)d_in[9];
    const float* w1     = (const float*)d_in[10];
    const float* q1     = (const float*)d_in[11];
    const float* k1     = (const float*)d_in[12];
    const float* b1     = (const float*)d_in[13];
    const float* lin_W  = (const float*)d_in[14];
    const float* lin_b  = (const float*)d_in[15];
    const float* clf_W  = (const float*)d_in[16];
    const float* clf_b  = (const float*)d_in[17];

    const int* srcp = eidx;
    const int* dstp = eidx + NE;

    char* wsb = (char*)d_ws;
    ushort16* h_bf    = (ushort16*)wsb;                 wsb += (size_t)NN * HID * 2;
    ushort16* hall_bf = (ushort16*)wsb;                 wsb += (size_t)NREL * NN * HID * 2;
    float*    h_f     = (float*)wsb;                    wsb += (size_t)NN * HID * 4;
    float*    sbuf    = (float*)wsb;                    wsb += (size_t)16 * NN * 4;
    float*    wqk     = (float*)wsb;                    wsb += 16 * HID * 4;
    float*    pooled  = (float*)wsb;                    wsb += NG * HID * 4;
    int*      cnt     = (int*)wsb;                      wsb += (size_t)NN * 4;
    int*      rowptr  = (int*)wsb;                      wsb += (size_t)(NN + 64) * 4;
    int*      bsum    = (int*)wsb;                      wsb += 256 * 4;
    uint32*   edges_s = (uint32*)wsb;                   wsb += (size_t)(NE + 64) * 4;

    const int NB = (NN + 255) / 256;   // 196

    // ---- CSR build ----
    hipMemsetAsync(cnt, 0, (size_t)NN * 4, stream);
    count_kernel<<<(NE + 255) / 256, 256, 0, stream>>>(dstp, cnt);
    scanA<<<NB, 256, 0, stream>>>(cnt, rowptr, bsum);
    scanB<<<1, 256, 0, stream>>>(bsum, NB);
    scanC<<<NB, 256, 0, stream>>>(rowptr, bsum);
    hipMemsetAsync(cnt, 0, (size_t)NN * 4, stream);
    scatter_kernel<<<(NE + 255) / 256, 256, 0, stream>>>(srcp, dstp, etype, rowptr, cnt, edges_s);

    // ---- encoder ----
    enc_mfma<<<256, 256, 0, stream>>>(x, enc_W, enc_b, h_bf);

    // ---- layer 0 ----
    wqk_kernel<<<16, 64, 0, stream>>>(w0, q0, k0, wqk);
    s_kernel<<<NN / 16, 256, 0, stream>>>(h_bf, wqk, sbuf);
    hall_mfma<<<dim3(256, NREL), 256, 0, stream>>>(h_bf, w0, hall_bf);
    agg_kernel<<<(NN + 3) / 4, 256, 0, stream>>>(rowptr, edges_s, sbuf, hall_bf, b0,
                                                 h_bf, (float*)nullptr, 1);

    // ---- layer 1 ----
    wqk_kernel<<<16, 64, 0, stream>>>(w1, q1, k1, wqk);
    s_kernel<<<NN / 16, 256, 0, stream>>>(h_bf, wqk, sbuf);
    hall_mfma<<<dim3(256, NREL), 256, 0, stream>>>(h_bf, w1, hall_bf);
    agg_kernel<<<(NN + 3) / 4, 256, 0, stream>>>(rowptr, edges_s, sbuf, hall_bf, b1,
                                                 (ushort16*)nullptr, h_f, 0);

    // ---- pool + head ----
    hipMemsetAsync(pooled, 0, (size_t)NG * HID * 4, stream);
    pool_kernel<<<(NN / 16 * HID + 255) / 256, 256, 0, stream>>>(h_f, batch, pooled);
    head_kernel<<<1, 256, 0, stream>>>(pooled, lin_W, lin_b, clf_W, clf_b, (float*)d_out);
}